// Round 11
// baseline (93.492 us; speedup 1.0000x reference)
//
#include <hip/hip_runtime.h>
#include <math.h>

#define S 4096
#define EPS 1e-5f

// ws float-index offsets
#define WS_PSUM 0            // [64]
#define WS_PSQ  64           // [64]
#define WS_ATT  16384        // [64*4096] f32
// ws byte offsets for f16 regions (each 512 KB)
#define QT_B 1310720
#define KT_B 1835008
#define VB_B 2359296

typedef _Float16 h8_t __attribute__((ext_vector_type(8)));
typedef __fp16   fp16v2 __attribute__((ext_vector_type(2)));
typedef float    f4_t  __attribute__((ext_vector_type(4)));
typedef float    f16_t __attribute__((ext_vector_type(16)));

union H8 { h8_t h; int4 v; int i[4]; };

static __device__ __forceinline__ int pkrtz(float a, float b) {
    fp16v2 p = __builtin_amdgcn_cvt_pkrtz(a, b);
    union { fp16v2 h; int i; } u; u.h = p; return u.i;
}

// Schraudolph: f16 bits of ~2^x = (int)(1024*x + 15360 - 44).
// 2 full-rate VALU ops; no pkrtz needed (bits ARE the f16). Validated R10.
#define EXP2_BITS(x) ((int)fmaf((x), 1024.0f, 15316.0f))

// ---------------- GroupNorm stage 1: per-channel partial sums ----------------
__global__ __launch_bounds__(256) void k_gnstat1(const float* __restrict__ x,
                                                 float* __restrict__ ws) {
    int b = blockIdx.x;
    int tid = threadIdx.x;
    const float4* p = (const float4*)(x + b * 4096);
    float s = 0.f, sq = 0.f;
    #pragma unroll
    for (int i = 0; i < 4; ++i) {
        float4 v = p[tid + i * 256];
        s  += v.x + v.y + v.z + v.w;
        sq += v.x * v.x + v.y * v.y + v.z * v.z + v.w * v.w;
    }
    #pragma unroll
    for (int m = 32; m >= 1; m >>= 1) {
        s  += __shfl_xor(s, m);
        sq += __shfl_xor(sq, m);
    }
    __shared__ float ls[4], lq[4];
    int w = tid >> 6;
    if ((tid & 63) == 0) { ls[w] = s; lq[w] = sq; }
    __syncthreads();
    if (tid == 0) {
        ws[WS_PSUM + b] = ls[0] + ls[1] + ls[2] + ls[3];
        ws[WS_PSQ  + b] = lq[0] + lq[1] + lq[2] + lq[3];
    }
}

// ---------------- QKV projection (GN fold fused), writes f16 MFMA layouts ----------------
// grid (16, 48), block 256: s-tile 256 (1 s/thread), o-tile 4 (half head-slice)
__global__ __launch_bounds__(256) void k_qkv(const float* __restrict__ x,
                                             const float* __restrict__ qkvw,
                                             const float* __restrict__ gnw,
                                             const float* __restrict__ gnb,
                                             float* __restrict__ ws) {
    __shared__ float la[64], lb2[64], lw[256], lbias[4];
    int tid = threadIdx.x;
    int o0 = blockIdx.y * 4;
    int s = blockIdx.x * 256 + tid;

    if (tid < 64) {                 // finalize GN stats (redundant per block, cheap)
        float sm = ws[WS_PSUM + tid];
        float sq = ws[WS_PSQ + tid];
        #pragma unroll
        for (int m = 1; m < 8; m <<= 1) {
            sm += __shfl_xor(sm, m);
            sq += __shfl_xor(sq, m);
        }
        const float inv_n = 1.0f / 32768.0f;
        float mu  = sm * inv_n;
        float var = sq * inv_n - mu * mu;
        float rs  = rsqrtf(var + EPS);
        float a   = rs * gnw[tid];
        la[tid]  = a;
        lb2[tid] = gnb[tid] - mu * a;
    }
    __syncthreads();
    lw[tid] = qkvw[o0 * 64 + tid] * la[tid & 63];
    {
        int wv = tid >> 6, ln = tid & 63;   // wave wv handles o = o0+wv
        float pb = qkvw[(o0 + wv) * 64 + ln] * lb2[ln];
        #pragma unroll
        for (int m = 1; m < 64; m <<= 1) pb += __shfl_xor(pb, m);
        if (ln == 0) lbias[wv] = pb;
    }
    __syncthreads();

    float acc[4];
    #pragma unroll
    for (int o = 0; o < 4; ++o) acc[o] = lbias[o];
    for (int c = 0; c < 64; ++c) {
        float xv = x[c * S + s];
        #pragma unroll
        for (int o = 0; o < 4; ++o) acc[o] = fmaf(lw[o * 64 + c], xv, acc[o]);
    }

    char* base = (char*)ws;
    if (o0 < 64) {                       // Q -> Qt[h][s][d], pre-scaled by 8^-0.5*log2(e)
        const float qsc = 0.51006776f;
        int hh = o0 >> 3, db = o0 & 7;   // db in {0,4}
        int2 r;
        r.x = pkrtz(acc[0] * qsc, acc[1] * qsc);
        r.y = pkrtz(acc[2] * qsc, acc[3] * qsc);
        *(int2*)(base + QT_B + (size_t)(hh * 4096 + s) * 16 + db * 2) = r;
    } else if (o0 < 128) {               // K -> Kt[h][t][d]
        int hh = (o0 - 64) >> 3, db = o0 & 7;
        int2 r;
        r.x = pkrtz(acc[0], acc[1]);
        r.y = pkrtz(acc[2], acc[3]);
        *(int2*)(base + KT_B + (size_t)(hh * 4096 + s) * 16 + db * 2) = r;
    } else {                             // V -> Vb[h][d][t]
        int hh = (o0 - 128) >> 3, db = o0 & 7;
        _Float16* vb = (_Float16*)(base + VB_B);
        #pragma unroll
        for (int d = 0; d < 4; ++d)
            vb[(size_t)((hh * 8 + db + d) * 4096) + s] = (_Float16)acc[d];
    }
}

// ---------------- Attention: f16 MFMA, 1-stage SW-pipelined P ---------------
// grid (128, 8), block 512: 32 queries/block, 8 waves = 8 t-chunks of 512.
// R5-R10 all kept write->read-same-iter on P (RAW LDS round-trip ~450cyc on
// the critical path every iteration — the invariant behind the stuck time).
// Now: iter it computes QK->exp->write P[it] into buf it&1; PV consumes
// P[it-1] from the OTHER buf (read issued at iter top, its writes completed
// a full iteration ago) with V[it-1] kept in registers. Two parallel chains.
__global__ __launch_bounds__(512, 4) void k_attn(float* __restrict__ ws) {
    const int h = blockIdx.y;
    const int q0 = blockIdx.x * 32;
    const int tid = threadIdx.x;
    const int w = tid >> 6;          // 0..7 t-chunk
    const int lane = tid & 63;
    const int col16 = lane & 15;
    const int quad = lane >> 4;
    const int col32 = lane & 31;
    const int half = lane >> 5;

    const char* base = (const char*)ws;
    const _Float16* Qt = (const _Float16*)(base + QT_B) + (size_t)h * 4096 * 8;
    const _Float16* Kt = (const _Float16*)(base + KT_B) + (size_t)h * 4096 * 8;
    const _Float16* Vb = (const _Float16*)(base + VB_B) + (size_t)h * 8 * 4096;

    // per wave: 2 P buffers of 32x40 halves = 5120 B -> 40960 B total.
    // red (14336 B) aliases the region after the loop (synced).
    __shared__ __align__(16) char smem[40960];
    _Float16* Pb0 = (_Float16*)smem + (size_t)w * 2560;
    _Float16* Pb1 = Pb0 + 1280;
    f4_t* red = (f4_t*)smem;

    // Q B-frag (32x32x16): lane<32 holds Q[s=col32][d=0..7]; upper half zero
    H8 qf;
    qf.i[0] = qf.i[1] = qf.i[2] = qf.i[3] = 0;
    if (half == 0) qf.v = *(const int4*)(Qt + (size_t)(q0 + col32) * 8);

    // K A-frag: lane<32 holds K[t=col32][d=0..7]; upper half stays zero
    H8 kf;
    kf.i[0] = kf.i[1] = kf.i[2] = kf.i[3] = 0;
    // V A-frag (16x16x32): rows m=d: d<8 data, d==8 ones (denominator), else 0
    H8 vf, vprev;
    {
        int c8 = (col16 == 8) ? 0x3C003C00 : 0;
        vf.i[0] = c8; vf.i[1] = c8; vf.i[2] = c8; vf.i[3] = c8;
    }
    vprev = vf;

    const int tbase = w * 512;
    if (half == 0) kf.v = *(const int4*)(Kt + (size_t)(tbase + col32) * 8);
    if (col16 < 8) vf.v = *(const int4*)(Vb + (size_t)col16 * 4096 + tbase + quad * 8);

    f4_t acc0 = {0.f, 0.f, 0.f, 0.f};
    f4_t acc1 = {0.f, 0.f, 0.f, 0.f};
    f16_t zc = {0.f, 0.f, 0.f, 0.f, 0.f, 0.f, 0.f, 0.f,
                0.f, 0.f, 0.f, 0.f, 0.f, 0.f, 0.f, 0.f};

    // ---- peel iter 0: QK -> exp -> write P0 (no PV yet) ----
    {
        f16_t sc = __builtin_amdgcn_mfma_f32_32x32x16_f16(kf.h, qf.h, zc, 0, 0, 0);
        H8 nk = kf, nv = vf;
        if (half == 0) nk.v = *(const int4*)(Kt + (size_t)(tbase + 32 + col32) * 8);
        if (col16 < 8) nv.v = *(const int4*)(Vb + (size_t)col16 * 4096 + tbase + 32 + quad * 8);
        #pragma unroll
        for (int b = 0; b < 4; ++b) {
            int i0 = EXP2_BITS(sc[4 * b + 0]);
            int i1 = EXP2_BITS(sc[4 * b + 1]);
            int i2 = EXP2_BITS(sc[4 * b + 2]);
            int i3 = EXP2_BITS(sc[4 * b + 3]);
            int2 wv = { i0 | (i1 << 16), i2 | (i3 << 16) };
            *(int2*)(Pb0 + col32 * 40 + 8 * b + 4 * half) = wv;
        }
        vprev = vf; kf = nk; vf = nv;
    }

    // ---- steady state: it = 1..15 ----
    for (int it = 1; it < 16; ++it) {
        const int tt = tbase + it * 32;
        _Float16* Pcur  = (it & 1) ? Pb1 : Pb0;
        _Float16* Pprev = (it & 1) ? Pb0 : Pb1;

        // chain A start: QK for THIS iter
        f16_t sc = __builtin_amdgcn_mfma_f32_32x32x16_f16(kf.h, qf.h, zc, 0, 0, 0);

        // prefetch K/V for NEXT iter (it=15 reads junk inside ws; unused)
        H8 nk = kf, nv = vf;
        if (half == 0) nk.v = *(const int4*)(Kt + (size_t)(tt + 32 + col32) * 8);
        if (col16 < 8) nv.v = *(const int4*)(Vb + (size_t)col16 * 4096 + tt + 32 + quad * 8);

        // chain B: read P[it-1] (writes completed a full iter ago) -> PV
        H8 p0, p1;
        p0.v = *(const int4*)(Pprev + col16 * 40 + quad * 8);
        p1.v = *(const int4*)(Pprev + (col16 + 16) * 40 + quad * 8);
        acc0 = __builtin_amdgcn_mfma_f32_16x16x32_f16(vprev.h, p0.h, acc0, 0, 0, 0);
        acc1 = __builtin_amdgcn_mfma_f32_16x16x32_f16(vprev.h, p1.h, acc1, 0, 0, 0);

        // chain A end: exp -> write P[it]
        #pragma unroll
        for (int b = 0; b < 4; ++b) {
            int i0 = EXP2_BITS(sc[4 * b + 0]);
            int i1 = EXP2_BITS(sc[4 * b + 1]);
            int i2 = EXP2_BITS(sc[4 * b + 2]);
            int i3 = EXP2_BITS(sc[4 * b + 3]);
            int2 wv = { i0 | (i1 << 16), i2 | (i3 << 16) };
            *(int2*)(Pcur + col32 * 40 + 8 * b + 4 * half) = wv;
        }

        vprev = vf; kf = nk; vf = nv;
    }

    // ---- drain: PV for iter 15 (P in Pb1, V15 in vprev) ----
    {
        H8 p0, p1;
        p0.v = *(const int4*)(Pb1 + col16 * 40 + quad * 8);
        p1.v = *(const int4*)(Pb1 + (col16 + 16) * 40 + quad * 8);
        acc0 = __builtin_amdgcn_mfma_f32_16x16x32_f16(vprev.h, p0.h, acc0, 0, 0, 0);
        acc1 = __builtin_amdgcn_mfma_f32_16x16x32_f16(vprev.h, p1.h, acc1, 0, 0, 0);
    }

    __syncthreads();   // all P traffic done; alias region as `red`
    if (w > 0) {
        red[((w - 1) * 2 + 0) * 64 + lane] = acc0;
        red[((w - 1) * 2 + 1) * 64 + lane] = acc1;
    }
    __syncthreads();
    if (w == 0) {
        #pragma unroll
        for (int r = 0; r < 7; ++r) {
            acc0 += red[(r * 2 + 0) * 64 + lane];
            acc1 += red[(r * 2 + 1) * 64 + lane];
        }
        float inv0 = 1.0f / __shfl(acc0[0], 32 + col16, 64);  // row d=8 = denom
        float inv1 = 1.0f / __shfl(acc1[0], 32 + col16, 64);
        if (quad < 2) {
            float* att = ws + WS_ATT + (size_t)(h * 8 + quad * 4) * S + q0;
            #pragma unroll
            for (int r = 0; r < 4; ++r) {
                att[r * S + col16]      = acc0[r] * inv0;
                att[r * S + 16 + col16] = acc1[r] * inv1;
            }
        }
    }
}

// ---------------- Out projection + bias + residual ----------------
// grid (16, 64), block 256: s-tile 256 (1 s/thread), o-tile 1 -> 1024 blocks
__global__ __launch_bounds__(256) void k_out(const float* __restrict__ x,
                                             const float* __restrict__ outw,
                                             const float* __restrict__ outb,
                                             const float* __restrict__ ws,
                                             float* __restrict__ out) {
    __shared__ float lw[64];
    int tid = threadIdx.x;
    int o = blockIdx.y;
    int s = blockIdx.x * 256 + tid;
    if (tid < 64) lw[tid] = outw[o * 64 + tid];
    __syncthreads();

    float acc = outb[o];
    const float* att = ws + WS_ATT;
    for (int c = 0; c < 64; ++c)
        acc = fmaf(lw[c], att[c * S + s], acc);
    out[o * S + s] = acc + x[o * S + s];
}

extern "C" void kernel_launch(void* const* d_in, const int* in_sizes, int n_in,
                              void* d_out, int out_size, void* d_ws, size_t ws_size,
                              hipStream_t stream) {
    const float* x    = (const float*)d_in[0];
    const float* gnw  = (const float*)d_in[1];
    const float* gnb  = (const float*)d_in[2];
    const float* qkvw = (const float*)d_in[3];
    const float* outw = (const float*)d_in[4];
    const float* outb = (const float*)d_in[5];
    float* out = (float*)d_out;
    float* ws  = (float*)d_ws;

    hipLaunchKernelGGL(k_gnstat1, dim3(64), dim3(256), 0, stream, x, ws);
    hipLaunchKernelGGL(k_qkv, dim3(16, 48), dim3(256), 0, stream, x, qkvw, gnw, gnb, ws);
    hipLaunchKernelGGL(k_attn, dim3(128, 8), dim3(512), 0, stream, ws);
    hipLaunchKernelGGL(k_out, dim3(16, 64), dim3(256), 0, stream, x, outw, outb, ws, out);
}